// Round 1
// baseline (175.071 us; speedup 1.0000x reference)
//
#include <hip/hip_runtime.h>
#include <hip/hip_bf16.h>

// GCN layer: out = (D^-1/2 A D^-1/2 X) W^T + b
// Round 11: decouple xs from the degree computation.
//   - xs = bf16(x) (UNSCALED) -> no dependency on binning -> cast moves into
//     k_binA's grid as extra streaming blocks (overlaps latency-bound binning).
//   - dis[col] is applied per-edge in k_fused: cc[u] is wave-uniform (from
//     readlane) so dis[cc[u]] is an s_load broadcast (200KB, L2-resident);
//     accumulate switches add -> fmac with SGPR operand. ~free.
//   - k_binB loses the 25.6MB x read + 12.85MB xs write from the serial
//     chain; now only: pairs read, LDS ELL build, coalesced dump, dis/degc.
//   - dis sized N+1, dis[N]=0 (pad slots gather row N and load dis[N]).
//
// ws: gbin | ell[N'*64 u16] 6.4MB | pairs[196*4608 u32] 3.6MB | dis[N+1] |
//     degc | xs[N'*128 bf16] 12.85MB | wb 32KB  ~= 23.2 MB

typedef short v8s __attribute__((ext_vector_type(8)));
typedef float v4f __attribute__((ext_vector_type(4)));

#define ELLCAP 64      // deg ~ Poisson(16); P(deg>64) ~ 1e-19/node. Guarded.
#define BINCAP 4608    // bin ~ Poisson(4082); cap at +8 sigma. Guarded.
#define ROWSTRIDE 136  // 128 bf16 + 8 pad shorts; 272 B rows (16B-aligned)

static __device__ __forceinline__ unsigned int f2bf(float f) {
    __hip_bfloat16 h = __float2bfloat16(f);  // RNE
    return (unsigned int)__builtin_bit_cast(unsigned short, h);
}

// Pass A: blocks [0,16) cast W; blocks [16,16+nbins) cast x -> bf16 xs
// (unscaled, pad rows zeroed); the rest bin 2048 edges each via LDS
// histogram + per-bin global reservation + scatter.
__global__ __launch_bounds__(256) void k_binA(
    const int* __restrict__ idx, int* __restrict__ gbin,
    unsigned int* __restrict__ pairs, const float4* __restrict__ w4,
    ushort4* __restrict__ wb4, const float2* __restrict__ x2,
    unsigned int* __restrict__ xs32, float* __restrict__ dis,
    int E, int nbins, int N) {
    int b = blockIdx.x;
    const int t = threadIdx.x;
    if (b < 16) {  // W cast: 16 blocks x 256 thr = 4096 float4s
        if (b == 0 && t == 0) dis[N] = 0.f;  // pad row: finite scale
        int i = b * 256 + t;
        float4 v = w4[i];
        ushort4 o;
        o.x = (unsigned short)f2bf(v.x);
        o.y = (unsigned short)f2bf(v.y);
        o.z = (unsigned short)f2bf(v.z);
        o.w = (unsigned short)f2bf(v.w);
        wb4[i] = o;
        return;
    }
    b -= 16;
    if (b < nbins) {  // xs cast: 256 rows per block, unscaled bf16
        size_t xbase = (size_t)b * 16384;
        int rbase = b * 256;
        for (int i = t; i < 16384; i += 256) {
            int lr = i >> 6;
            unsigned ov = 0u;
            if (rbase + lr < N) {
                float2 v = x2[xbase + i];
                ov = f2bf(v.x) | (f2bf(v.y) << 16);
            }
            xs32[xbase + i] = ov;  // rows >= N (incl. pad row N) -> zeros
        }
        return;
    }
    b -= nbins;
    __shared__ int hist[256];
    __shared__ int base[256];
    hist[t] = 0;
    __syncthreads();

    int e0 = b * 2048 + t * 8;
    int nv = E - e0;
    nv = nv > 8 ? 8 : (nv < 0 ? 0 : nv);
    int rows[8], cols[8];
    if (nv == 8) {
        int4 a0 = *(const int4*)&idx[e0];
        int4 a1 = *(const int4*)&idx[e0 + 4];
        int4 c0 = *(const int4*)&idx[E + e0];
        int4 c1 = *(const int4*)&idx[E + e0 + 4];
        rows[0] = a0.x; rows[1] = a0.y; rows[2] = a0.z; rows[3] = a0.w;
        rows[4] = a1.x; rows[5] = a1.y; rows[6] = a1.z; rows[7] = a1.w;
        cols[0] = c0.x; cols[1] = c0.y; cols[2] = c0.z; cols[3] = c0.w;
        cols[4] = c1.x; cols[5] = c1.y; cols[6] = c1.z; cols[7] = c1.w;
    } else {
        for (int k = 0; k < 8; ++k) {
            rows[k] = (k < nv) ? idx[e0 + k] : 0;
            cols[k] = (k < nv) ? idx[E + e0 + k] : 0;
        }
    }
#pragma unroll
    for (int k = 0; k < 8; ++k)
        if (k < nv) atomicAdd(&hist[rows[k] >> 8], 1);
    __syncthreads();
    if (t < nbins) base[t] = atomicAdd(&gbin[t], hist[t]);  // 196/block
    __syncthreads();
    hist[t] = 0;
    __syncthreads();
#pragma unroll
    for (int k = 0; k < 8; ++k) {
        if (k < nv) {
            int bin = rows[k] >> 8;
            int pos = base[bin] + atomicAdd(&hist[bin], 1);
            if (pos < BINCAP)
                pairs[(size_t)bin * BINCAP + pos] =
                    (unsigned)(((rows[k] & 255) << 16) | cols[k]);
        }
    }
}

// Pass B: one block per bin (256 rows). Build ELL in LDS (LDS atomics),
// coalesced dump; true-degree dis/degc. No x traffic anymore.
__global__ __launch_bounds__(1024) void k_binB(
    const unsigned int* __restrict__ pairs, const int* __restrict__ gbin,
    unsigned short* __restrict__ ell, unsigned char* __restrict__ degc,
    float* __restrict__ dis, int N) {
    __shared__ __align__(16) unsigned short lell[256 * ELLCAP];  // 32 KB
    __shared__ int cnt_l[256];
    const int bin = blockIdx.x;
    const int t = threadIdx.x;
    if (t < 256) cnt_l[t] = 0;
    __syncthreads();

    int m = gbin[bin];
    if (m > BINCAP) m = BINCAP;
    for (int i = t; i < m; i += 1024) {
        unsigned pv = pairs[(size_t)bin * BINCAP + i];
        int local = pv >> 16;
        int slot = atomicAdd(&cnt_l[local], 1);  // LDS atomic; true count
        if (slot < ELLCAP) lell[local * ELLCAP + slot] = (unsigned short)(pv & 0xFFFF);
    }
    __syncthreads();

    if (t < 256) {
        int r = bin * 256 + t;
        if (r < N) {
            int d = cnt_l[t];
            float s = (d > 0) ? rsqrtf((float)d) : 0.0f;  // TRUE degree
            dis[r] = s;
            degc[r] = (unsigned char)(d > ELLCAP ? ELLCAP : d);
        } else if (r == N) {
            dis[N] = 0.f;  // pad row (also written by binA block 0)
        }
    }
    __syncthreads();

    // coalesced ELL dump: 32 KB = 8192 dwords (garbage slots never read)
    {
        unsigned int* gell = (unsigned int*)(ell + (size_t)bin * 256 * ELLCAP);
        const unsigned int* sell = (const unsigned int*)lell;
        for (int i = t; i < 8192; i += 1024) gell[i] = sell[i];
    }
}

// Fused gather + GEMM. Block = 4 waves, 32 output rows.
// Gather: one wave/node, lane owns 1 dword (2 bf16 ch). Pad slots -> row N
// (zeros, dis[N]=0). Per-edge dis[col] via uniform s_load broadcast; inner
// loop: 16 readlanes + 16 vector loads + 16 scalar loads in flight + 32 fmac.
__global__ __launch_bounds__(256) void k_fused(
    const unsigned short* __restrict__ ell, const unsigned char* __restrict__ degc,
    const float* __restrict__ dis, const unsigned int* __restrict__ xs32,
    const v8s* __restrict__ Wb8, const float* __restrict__ bias,
    float* __restrict__ out, int N) {
    __shared__ __align__(16) unsigned short smem[32 * ROWSTRIDE];
    const int nb0 = blockIdx.x * 32;
    const int wv = threadIdx.x >> 6, lane = threadIdx.x & 63;

    for (int i = 0; i < 8; ++i) {
        int lrow = wv * 8 + i;
        int n = nb0 + lrow;
        float acc0 = 0.f, acc1 = 0.f;
        if (n < N) {
            int d = degc[n];
            int cl = ell[(size_t)n * ELLCAP + lane];  // stale slots never used
            int c = (lane < d) ? cl : N;              // pad -> zero row
            for (int j = 0; j < d; j += 16) {         // j in {0,16,32,48}
                int cc[16];
#pragma unroll
                for (int u = 0; u < 16; ++u)
                    cc[u] = __builtin_amdgcn_readlane(c, j + u);  // uniform
                unsigned uu[16];
#pragma unroll
                for (int u = 0; u < 16; ++u)
                    uu[u] = xs32[(size_t)cc[u] * 64 + lane];
                float dcv[16];
#pragma unroll
                for (int u = 0; u < 16; ++u)
                    dcv[u] = dis[cc[u]];  // uniform -> s_load broadcast
#pragma unroll
                for (int u = 0; u < 16; ++u) {
                    acc0 = fmaf(dcv[u], __builtin_bit_cast(float, uu[u] << 16), acc0);
                    acc1 = fmaf(dcv[u], __builtin_bit_cast(float, uu[u] & 0xFFFF0000u), acc1);
                }
            }
            float s = dis[n];
            acc0 *= s;
            acc1 *= s;
        }
        unsigned pack = f2bf(acc0) | (f2bf(acc1) << 16);
        *(unsigned int*)&smem[(size_t)lrow * ROWSTRIDE + lane * 2] = pack;
    }
    __syncthreads();

    // MFMA (verified layout: A m=lane&15 k=quad*8+i; B row-major W bf16;
    // C/D col=lane&15 row=quad*4+reg). Wave: rows (wv&1)*16, cols (wv>>1)*64.
    {
        int quad = lane >> 4, m16 = lane & 15;
        int lrow = (wv & 1) * 16 + m16;
        v8s afrag[4];
#pragma unroll
        for (int kk = 0; kk < 4; ++kk)
            afrag[kk] = *(const v8s*)&smem[lrow * ROWSTRIDE + kk * 32 + quad * 8];
        int rbase = nb0 + (wv & 1) * 16 + quad * 4;
        int jbase = (wv >> 1) * 64;
#pragma unroll
        for (int jt = 0; jt < 4; ++jt) {
            int jcol = jbase + jt * 16 + m16;
            v4f acc = {0.f, 0.f, 0.f, 0.f};
#pragma unroll
            for (int kk = 0; kk < 4; ++kk) {
                v8s bfrag = Wb8[jcol * 16 + kk * 4 + quad];
                acc = __builtin_amdgcn_mfma_f32_16x16x32_bf16(afrag[kk], bfrag,
                                                              acc, 0, 0, 0);
            }
            float bj = bias[jcol];
#pragma unroll
            for (int r = 0; r < 4; ++r) {
                int row = rbase + r;
                if (row < N) out[(size_t)row * 128 + jcol] = acc[r] + bj;
            }
        }
    }
}

extern "C" void kernel_launch(void* const* d_in, const int* in_sizes, int n_in,
                              void* d_out, int out_size, void* d_ws, size_t ws_size,
                              hipStream_t stream) {
    const float* x = (const float*)d_in[0];
    const int* idx = (const int*)d_in[1];
    const float* W = (const float*)d_in[2];
    const float* b = (const float*)d_in[3];
    float* out = (float*)d_out;

    const int N = in_sizes[0] / 128;      // 50000
    const int E = in_sizes[1] / 2;        // 800000
    const int nbins = (N + 255) / 256;    // 196 (<= 256 required)
    const int nrows = nbins * 256;        // 50176 (covers pad row N)

    char* p = (char*)d_ws;
    auto alloc = [&](size_t bytes) {
        char* r = p;
        p += (bytes + 63) & ~(size_t)63;
        return r;
    };
    int* gbin = (int*)alloc((size_t)nbins * 4);
    unsigned short* ell = (unsigned short*)alloc((size_t)nrows * ELLCAP * 2);  // 6.4 MB
    unsigned int* pairs = (unsigned int*)alloc((size_t)nbins * BINCAP * 4);    // 3.6 MB
    float* dis = (float*)alloc((size_t)(N + 1) * 4);
    unsigned char* degc = (unsigned char*)alloc((size_t)N);
    unsigned int* xs = (unsigned int*)alloc((size_t)nrows * 128 * 2);  // 12.85 MB
    ushort4* wb = (ushort4*)alloc(128 * 128 * 2);                      // 32 KB

    hipMemsetAsync(gbin, 0, (size_t)nbins * sizeof(int), stream);

    // 16 W-cast + 196 xs-cast + 391 binning blocks, all concurrent
    const int ablocks = 16 + nbins + (E + 2047) / 2048;
    k_binA<<<ablocks, 256, 0, stream>>>(idx, gbin, pairs, (const float4*)W, wb,
                                        (const float2*)x, xs, dis, E, nbins, N);
    k_binB<<<nbins, 1024, 0, stream>>>(pairs, gbin, ell, degc, dis, N);
    k_fused<<<(N + 31) / 32, 256, 0, stream>>>(ell, degc, dis, xs, (const v8s*)wb,
                                               b, out, N);
}

// Round 2
// 174.296 us; speedup vs baseline: 1.0044x; 1.0044x over previous
//
#include <hip/hip_runtime.h>
#include <hip/hip_bf16.h>

// GCN layer: out = (D^-1/2 A D^-1/2 X) W^T + b
// Round 12: collapse the 3-stage (binA binning -> binB ELL build -> fused)
// pipeline into 2 stages:
//   k_build: W cast + xs=bf16(x) cast (unscaled) + DIRECT atomic ELL build
//     (slot = atomicAdd(&deg[row],1); ell[row*64+slot]=col). The 800K
//     returning atomics (~50us fabric floor, R5/R9 evidence) run with the
//     38MB cast streaming overlapped into otherwise-idle BW (binA showed 8%
//     BW, 2% VALU during binning).
//   k_fused: gather+MFMA. dis array eliminated: per-row rsqrt(deg[n])
//     (uniform s_load), per-edge dis[col] via per-lane deg[c] gather + VALU
//     rsqrt hoisted BEFORE the loop, broadcast by v_readlane (register-only)
//     -- replaces R11's 16 s_load/group chain that cost +6us.
//   deg sized N+1, deg[N]=0 (memset) -> pad lanes and zero-deg cols scale 0.
//
// ws: deg[(N+1) i32] 200KB | ell[N*64 u16] 6.4MB | xs[nrows*128 bf16]
//     12.85MB | wb 32KB  ~= 19.5 MB

typedef short v8s __attribute__((ext_vector_type(8)));
typedef float v4f __attribute__((ext_vector_type(4)));

#define ELLCAP 64      // deg ~ Poisson(16); P(deg>64) ~ 1e-19/node. Guarded.
#define ROWSTRIDE 136  // 128 bf16 + 8 pad shorts; 272 B rows (16B-aligned)

static __device__ __forceinline__ unsigned int f2bf(float f) {
    __hip_bfloat16 h = __float2bfloat16(f);  // RNE
    return (unsigned int)__builtin_bit_cast(unsigned short, h);
}

// k_build: blocks [0,16): W cast. [16,16+ncast): xs cast (4096 dwords each,
// 16 iters of 256 threads). Rest: 2048 edges each, direct atomic ELL build.
__global__ __launch_bounds__(256) void k_build(
    const int* __restrict__ idx, int* __restrict__ deg,
    unsigned short* __restrict__ ell, const float4* __restrict__ w4,
    ushort4* __restrict__ wb4, const float2* __restrict__ x2,
    unsigned int* __restrict__ xs32, int E, int ncast, int N) {
    int b = blockIdx.x;
    const int t = threadIdx.x;
    if (b < 16) {  // W cast: 16 blocks x 256 thr = 4096 float4s
        int i = b * 256 + t;
        float4 v = w4[i];
        ushort4 o;
        o.x = (unsigned short)f2bf(v.x);
        o.y = (unsigned short)f2bf(v.y);
        o.z = (unsigned short)f2bf(v.z);
        o.w = (unsigned short)f2bf(v.w);
        wb4[i] = o;
        return;
    }
    b -= 16;
    if (b < ncast) {  // xs cast: 4096 dwords (64 rows) per block, unscaled
        int base = b * 4096;
#pragma unroll 4
        for (int it = 0; it < 16; ++it) {
            int i = base + it * 256 + t;
            int lr = i >> 6;  // global row
            unsigned ov = 0u;
            if (lr < N) {
                float2 v = x2[i];
                ov = f2bf(v.x) | (f2bf(v.y) << 16);
            }
            xs32[i] = ov;  // rows >= N (incl. pad row N) -> zeros
        }
        return;
    }
    b -= ncast;
    // direct ELL build: 8 edges/thread, independent atomic chains
    int e0 = b * 2048 + t * 8;
    int nv = E - e0;
    nv = nv > 8 ? 8 : (nv < 0 ? 0 : nv);
    int rows[8], cols[8];
    if (nv == 8) {
        int4 a0 = *(const int4*)&idx[e0];
        int4 a1 = *(const int4*)&idx[e0 + 4];
        int4 c0 = *(const int4*)&idx[E + e0];
        int4 c1 = *(const int4*)&idx[E + e0 + 4];
        rows[0] = a0.x; rows[1] = a0.y; rows[2] = a0.z; rows[3] = a0.w;
        rows[4] = a1.x; rows[5] = a1.y; rows[6] = a1.z; rows[7] = a1.w;
        cols[0] = c0.x; cols[1] = c0.y; cols[2] = c0.z; cols[3] = c0.w;
        cols[4] = c1.x; cols[5] = c1.y; cols[6] = c1.z; cols[7] = c1.w;
    } else {
        for (int k = 0; k < 8; ++k) {
            rows[k] = (k < nv) ? idx[e0 + k] : 0;
            cols[k] = (k < nv) ? idx[E + e0 + k] : 0;
        }
    }
#pragma unroll
    for (int k = 0; k < 8; ++k) {
        if (k < nv) {
            int slot = atomicAdd(&deg[rows[k]], 1);  // true degree counter
            if (slot < ELLCAP)
                ell[(size_t)rows[k] * ELLCAP + slot] = (unsigned short)cols[k];
        }
    }
}

// Fused gather + GEMM. Block = 4 waves, 32 output rows.
// Gather: one wave/node, lane owns 1 dword (2 bf16 ch). Pad slots -> row N
// (zeros, deg[N]=0). Per-edge dis[col]: per-lane deg[c] gather + rsqrt
// hoisted before the loop, broadcast via readlane (register-only).
__global__ __launch_bounds__(256) void k_fused(
    const unsigned short* __restrict__ ell, const int* __restrict__ deg,
    const unsigned int* __restrict__ xs32, const v8s* __restrict__ Wb8,
    const float* __restrict__ bias, float* __restrict__ out, int N) {
    __shared__ __align__(16) unsigned short smem[32 * ROWSTRIDE];
    const int nb0 = blockIdx.x * 32;
    const int wv = threadIdx.x >> 6, lane = threadIdx.x & 63;

    for (int i = 0; i < 8; ++i) {
        int lrow = wv * 8 + i;
        int n = nb0 + lrow;
        float acc0 = 0.f, acc1 = 0.f;
        if (n < N) {
            int dtrue = deg[n];  // uniform -> s_load
            int d = dtrue > ELLCAP ? ELLCAP : dtrue;
            int cl = ell[(size_t)n * ELLCAP + lane];  // stale slots never used
            int c = (lane < d) ? cl : N;              // pad -> zero row
            // per-lane neighbor scale: deg[c] gather (L2-hot 200KB) + rsqrt
            int dc = deg[c];
            float invs = (dc > 0) ? rsqrtf((float)dc) : 0.f;
            int invb = __builtin_bit_cast(int, invs);
            for (int j = 0; j < d; j += 16) {  // j in {0,16,32,48}
                int cc[16];
#pragma unroll
                for (int u = 0; u < 16; ++u)
                    cc[u] = __builtin_amdgcn_readlane(c, j + u);
                unsigned uu[16];
#pragma unroll
                for (int u = 0; u < 16; ++u)
                    uu[u] = xs32[(size_t)cc[u] * 64 + lane];
                float sc[16];
#pragma unroll
                for (int u = 0; u < 16; ++u)
                    sc[u] = __builtin_bit_cast(
                        float, __builtin_amdgcn_readlane(invb, j + u));
#pragma unroll
                for (int u = 0; u < 16; ++u) {
                    acc0 = fmaf(sc[u], __builtin_bit_cast(float, uu[u] << 16), acc0);
                    acc1 = fmaf(sc[u],
                                __builtin_bit_cast(float, uu[u] & 0xFFFF0000u), acc1);
                }
            }
            float s = (dtrue > 0) ? rsqrtf((float)dtrue) : 0.f;
            acc0 *= s;
            acc1 *= s;
        }
        unsigned pack = f2bf(acc0) | (f2bf(acc1) << 16);
        *(unsigned int*)&smem[(size_t)lrow * ROWSTRIDE + lane * 2] = pack;
    }
    __syncthreads();

    // MFMA (verified layout: A m=lane&15 k=quad*8+i; B row-major W bf16;
    // C/D col=lane&15 row=quad*4+reg). Wave: rows (wv&1)*16, cols (wv>>1)*64.
    {
        int quad = lane >> 4, m16 = lane & 15;
        int lrow = (wv & 1) * 16 + m16;
        v8s afrag[4];
#pragma unroll
        for (int kk = 0; kk < 4; ++kk)
            afrag[kk] = *(const v8s*)&smem[lrow * ROWSTRIDE + kk * 32 + quad * 8];
        int rbase = nb0 + (wv & 1) * 16 + quad * 4;
        int jbase = (wv >> 1) * 64;
#pragma unroll
        for (int jt = 0; jt < 4; ++jt) {
            int jcol = jbase + jt * 16 + m16;
            v4f acc = {0.f, 0.f, 0.f, 0.f};
#pragma unroll
            for (int kk = 0; kk < 4; ++kk) {
                v8s bfrag = Wb8[jcol * 16 + kk * 4 + quad];
                acc = __builtin_amdgcn_mfma_f32_16x16x32_bf16(afrag[kk], bfrag,
                                                              acc, 0, 0, 0);
            }
            float bj = bias[jcol];
#pragma unroll
            for (int r = 0; r < 4; ++r) {
                int row = rbase + r;
                if (row < N) out[(size_t)row * 128 + jcol] = acc[r] + bj;
            }
        }
    }
}

extern "C" void kernel_launch(void* const* d_in, const int* in_sizes, int n_in,
                              void* d_out, int out_size, void* d_ws, size_t ws_size,
                              hipStream_t stream) {
    const float* x = (const float*)d_in[0];
    const int* idx = (const int*)d_in[1];
    const float* W = (const float*)d_in[2];
    const float* b = (const float*)d_in[3];
    float* out = (float*)d_out;

    const int N = in_sizes[0] / 128;    // 50000
    const int E = in_sizes[1] / 2;      // 800000
    const int nbins = (N + 255) / 256;  // 196
    const int nrows = nbins * 256;      // 50176 (covers pad row N)
    const int ncast = nbins * 4;        // 784 blocks x 4096 dwords = nrows*64

    char* p = (char*)d_ws;
    auto alloc = [&](size_t bytes) {
        char* r = p;
        p += (bytes + 63) & ~(size_t)63;
        return r;
    };
    int* deg = (int*)alloc((size_t)(N + 1) * 4);                        // 200 KB
    unsigned short* ell = (unsigned short*)alloc((size_t)N * ELLCAP * 2);  // 6.4 MB
    unsigned int* xs = (unsigned int*)alloc((size_t)nrows * 128 * 2);   // 12.85 MB
    ushort4* wb = (ushort4*)alloc(128 * 128 * 2);                       // 32 KB

    hipMemsetAsync(deg, 0, (size_t)(N + 1) * sizeof(int), stream);

    // 16 W-cast + 784 xs-cast + 391 ELL-build blocks, all concurrent
    const int bblocks = 16 + ncast + (E + 2047) / 2048;
    k_build<<<bblocks, 256, 0, stream>>>(idx, deg, ell, (const float4*)W, wb,
                                         (const float2*)x, xs, E, ncast, N);
    k_fused<<<(N + 31) / 32, 256, 0, stream>>>(ell, deg, xs, (const v8s*)wb, b,
                                               out, N);
}

// Round 3
// 158.700 us; speedup vs baseline: 1.1032x; 1.0983x over previous
//
#include <hip/hip_runtime.h>
#include <hip/hip_bf16.h>

// GCN layer: out = (D^-1/2 A D^-1/2 X) W^T + b
// Round 13: kill same-address returning-atomic serialization (the real floor
// mechanism in R10 binA / R12 k_build) by SHARDING bin counters 16-way:
//   k_bin: W cast + xs=bf16(x) cast (overlapped) + edge binning. Per-block
//     LDS hist -> 196 reservations into gbin[bin*16 + block&15] (contention
//     391 -> ~24 per address) -> packed (localrow<<16|col) scatter into the
//     block's shard sub-region.
//   k_deg: per bin, scan 16 sub-regions, LDS per-node count, write
//     dis[r] = rsqrt(deg[r]) (f32, 200KB, L2/L3-hot). dis[r>=N] = 0.
//   k_fused: 4 blocks/bin x 64 rows, 512 thr (8 waves). Scan the bin's
//     sub-regions, keep own 64 rows, build ELL in LDS (LDS atomics only;
//     no global ell array / no dump+reload). Gather: R12-verified inner
//     loop (per-lane dis[c] gather + readlane broadcast), MFMA epilogue
//     (verified layout) on two 32-row groups.
//
// ws: gbin[196*16] 12.5KB | pairs[196*16*384 u32] 4.8MB | dis[nrows f32]
//     200KB | xs[nrows*128 bf16] 12.85MB | wb 32KB  ~= 17.9 MB

typedef short v8s __attribute__((ext_vector_type(8)));
typedef float v4f __attribute__((ext_vector_type(4)));

#define ELLCAP 64     // deg ~ Poisson(16); P(deg>64) ~ 1e-19/node. Guarded.
#define NSHARD 16     // counter shards per bin
#define SUBCAP 384    // shard sub-region ~ Poisson(261 max); +7.6 sigma. Guarded.
#define ROWSTRIDE 136 // 128 bf16 + 8 pad shorts; 272 B rows (16B-aligned)

static __device__ __forceinline__ unsigned int f2bf(float f) {
    __hip_bfloat16 h = __float2bfloat16(f);  // RNE
    return (unsigned int)__builtin_bit_cast(unsigned short, h);
}

// k_bin: blocks [0,16): W cast. [16,16+ncast): xs cast (4096 dwords each).
// Rest: 2048 edges each; LDS hist -> sharded reservation -> packed scatter.
__global__ __launch_bounds__(256) void k_bin(
    const int* __restrict__ idx, int* __restrict__ gbin,
    unsigned int* __restrict__ pairs, const float4* __restrict__ w4,
    ushort4* __restrict__ wb4, const float2* __restrict__ x2,
    unsigned int* __restrict__ xs32, int E, int ncast, int N, int nbins) {
    int b = blockIdx.x;
    const int t = threadIdx.x;
    if (b < 16) {  // W cast: 16 blocks x 256 thr = 4096 float4s
        int i = b * 256 + t;
        float4 v = w4[i];
        ushort4 o;
        o.x = (unsigned short)f2bf(v.x);
        o.y = (unsigned short)f2bf(v.y);
        o.z = (unsigned short)f2bf(v.z);
        o.w = (unsigned short)f2bf(v.w);
        wb4[i] = o;
        return;
    }
    b -= 16;
    if (b < ncast) {  // xs cast: 4096 dwords (64 rows) per block, unscaled
        int base = b * 4096;
#pragma unroll 4
        for (int it = 0; it < 16; ++it) {
            int i = base + it * 256 + t;
            int lr = i >> 6;  // global row
            unsigned ov = 0u;
            if (lr < N) {
                float2 v = x2[i];
                ov = f2bf(v.x) | (f2bf(v.y) << 16);
            }
            xs32[i] = ov;  // rows >= N (incl. pad row N) -> zeros
        }
        return;
    }
    b -= ncast;
    __shared__ int hist[256];
    __shared__ int hist2[256];
    __shared__ int base[256];
    hist[t] = 0;
    hist2[t] = 0;
    __syncthreads();

    int e0 = b * 2048 + t * 8;
    int nv = E - e0;
    nv = nv > 8 ? 8 : (nv < 0 ? 0 : nv);
    int rows[8], cols[8];
    if (nv == 8) {
        int4 a0 = *(const int4*)&idx[e0];
        int4 a1 = *(const int4*)&idx[e0 + 4];
        int4 c0 = *(const int4*)&idx[E + e0];
        int4 c1 = *(const int4*)&idx[E + e0 + 4];
        rows[0] = a0.x; rows[1] = a0.y; rows[2] = a0.z; rows[3] = a0.w;
        rows[4] = a1.x; rows[5] = a1.y; rows[6] = a1.z; rows[7] = a1.w;
        cols[0] = c0.x; cols[1] = c0.y; cols[2] = c0.z; cols[3] = c0.w;
        cols[4] = c1.x; cols[5] = c1.y; cols[6] = c1.z; cols[7] = c1.w;
    } else {
        for (int k = 0; k < 8; ++k) {
            rows[k] = (k < nv) ? idx[e0 + k] : 0;
            cols[k] = (k < nv) ? idx[E + e0 + k] : 0;
        }
    }
#pragma unroll
    for (int k = 0; k < 8; ++k)
        if (k < nv) atomicAdd(&hist[rows[k] >> 8], 1);
    __syncthreads();
    const int shard = b & (NSHARD - 1);
    if (t < nbins)  // low contention: ~24 blocks share each counter address
        base[t] = atomicAdd(&gbin[t * NSHARD + shard], hist[t]);
    __syncthreads();
#pragma unroll
    for (int k = 0; k < 8; ++k) {
        if (k < nv) {
            int bin = rows[k] >> 8;
            int pos = base[bin] + atomicAdd(&hist2[bin], 1);
            if (pos < SUBCAP)
                pairs[((size_t)bin * NSHARD + shard) * SUBCAP + pos] =
                    (unsigned)(((rows[k] & 255) << 16) | cols[k]);
        }
    }
}

// k_deg: one block per bin. Scan 16 sub-regions, LDS-count per local node,
// write dis = rsqrt(deg) (0 for deg==0 and rows >= N, incl. pad row N).
__global__ __launch_bounds__(1024) void k_deg(
    const unsigned int* __restrict__ pairs, const int* __restrict__ gbin,
    float* __restrict__ dis, int N) {
    __shared__ int cnt[256];
    __shared__ int scnt[NSHARD];
    const int bin = blockIdx.x;
    const int t = threadIdx.x;
    if (t < 256) cnt[t] = 0;
    if (t < NSHARD) {
        int m = gbin[bin * NSHARD + t];
        scnt[t] = m > SUBCAP ? SUBCAP : m;
    }
    __syncthreads();
    for (int s = 0; s < NSHARD; ++s) {
        int ms = scnt[s];
        size_t pb = ((size_t)bin * NSHARD + s) * SUBCAP;
        for (int i = t; i < ms; i += 1024)
            atomicAdd(&cnt[pairs[pb + i] >> 16], 1);
    }
    __syncthreads();
    if (t < 256) {
        int r = bin * 256 + t;
        int d = cnt[t];
        dis[r] = (r < N && d > 0) ? rsqrtf((float)d) : 0.f;
    }
}

// k_fused: 4 blocks/bin, 64 rows each, 512 threads (8 waves).
// Phase 1: scan bin sub-regions, keep own rows, build 64-row ELL in LDS.
// Phase 2: gather (per-lane dis[c] + readlane broadcast). Phase 3: MFMA.
__global__ __launch_bounds__(512) void k_fused(
    const unsigned int* __restrict__ pairs, const int* __restrict__ gbin,
    const float* __restrict__ dis, const unsigned int* __restrict__ xs32,
    const v8s* __restrict__ Wb8, const float* __restrict__ bias,
    float* __restrict__ out, int N) {
    __shared__ __align__(16) unsigned short lell[64 * ELLCAP];  // 8 KB
    __shared__ int cnt[64];
    __shared__ int scnt[NSHARD];
    __shared__ __align__(16) unsigned short smem[64 * ROWSTRIDE];  // 17.4 KB
    const int bin = blockIdx.x >> 2, sub = blockIdx.x & 3;
    const int t = threadIdx.x;
    if (t < 64) cnt[t] = 0;
    if (t < NSHARD) {
        int m = gbin[bin * NSHARD + t];
        scnt[t] = m > SUBCAP ? SUBCAP : m;
    }
    __syncthreads();
    for (int s = 0; s < NSHARD; ++s) {
        int ms = scnt[s];
        size_t pb = ((size_t)bin * NSHARD + s) * SUBCAP;
        for (int i = t; i < ms; i += 512) {
            unsigned pv = pairs[pb + i];
            int lr = pv >> 16;
            if ((lr >> 6) == sub) {  // own 64-row slice of the bin
                int slot = atomicAdd(&cnt[lr & 63], 1);
                if (slot < ELLCAP)
                    lell[(lr & 63) * ELLCAP + slot] = (unsigned short)(pv & 0xFFFF);
            }
        }
    }
    __syncthreads();

    const int wv = t >> 6, lane = t & 63;
    const int r0 = bin * 256 + sub * 64;
    for (int i = 0; i < 8; ++i) {
        int lrow = wv * 8 + i;
        int n = r0 + lrow;
        float acc0 = 0.f, acc1 = 0.f;
        if (n < N) {
            int dtrue = cnt[lrow];
            int d = dtrue > ELLCAP ? ELLCAP : dtrue;
            int cl = lell[lrow * ELLCAP + lane];  // stale slots never used
            int c = (lane < d) ? cl : N;          // pad -> zero row, dis=0
            float dcf = dis[c];                   // per-lane, 200KB L2-hot
            int dcb = __builtin_bit_cast(int, dcf);
            for (int j = 0; j < d; j += 16) {  // j in {0,16,32,48}
                int cc[16];
#pragma unroll
                for (int u = 0; u < 16; ++u)
                    cc[u] = __builtin_amdgcn_readlane(c, j + u);
                unsigned uu[16];
#pragma unroll
                for (int u = 0; u < 16; ++u)
                    uu[u] = xs32[(size_t)cc[u] * 64 + lane];
                float sc[16];
#pragma unroll
                for (int u = 0; u < 16; ++u)
                    sc[u] = __builtin_bit_cast(
                        float, __builtin_amdgcn_readlane(dcb, j + u));
#pragma unroll
                for (int u = 0; u < 16; ++u) {
                    acc0 = fmaf(sc[u], __builtin_bit_cast(float, uu[u] << 16), acc0);
                    acc1 = fmaf(sc[u],
                                __builtin_bit_cast(float, uu[u] & 0xFFFF0000u), acc1);
                }
            }
            float s = (dtrue > 0) ? rsqrtf((float)dtrue) : 0.f;
            acc0 *= s;
            acc1 *= s;
        }
        unsigned pack = f2bf(acc0) | (f2bf(acc1) << 16);
        *(unsigned int*)&smem[(size_t)lrow * ROWSTRIDE + lane * 2] = pack;
    }
    __syncthreads();

    // MFMA (verified layout: A m=lane&15 k=quad*8+i; B row-major W bf16;
    // C/D col=lane&15 row=quad*4+reg). Two 32-row groups x 4 waves each:
    // group g=wv>>2; within group: rows (wv&1)*16, cols ((wv&3)>>1)*64.
    {
        int g = wv >> 2, w4 = wv & 3;
        int quad = lane >> 4, m16 = lane & 15;
        int lrow = g * 32 + (w4 & 1) * 16 + m16;
        v8s afrag[4];
#pragma unroll
        for (int kk = 0; kk < 4; ++kk)
            afrag[kk] = *(const v8s*)&smem[lrow * ROWSTRIDE + kk * 32 + quad * 8];
        int rbase = r0 + g * 32 + (w4 & 1) * 16 + quad * 4;
        int jbase = (w4 >> 1) * 64;
#pragma unroll
        for (int jt = 0; jt < 4; ++jt) {
            int jcol = jbase + jt * 16 + m16;
            v4f acc = {0.f, 0.f, 0.f, 0.f};
#pragma unroll
            for (int kk = 0; kk < 4; ++kk) {
                v8s bfrag = Wb8[jcol * 16 + kk * 4 + quad];
                acc = __builtin_amdgcn_mfma_f32_16x16x32_bf16(afrag[kk], bfrag,
                                                              acc, 0, 0, 0);
            }
            float bj = bias[jcol];
#pragma unroll
            for (int r = 0; r < 4; ++r) {
                int row = rbase + r;
                if (row < N) out[(size_t)row * 128 + jcol] = acc[r] + bj;
            }
        }
    }
}

extern "C" void kernel_launch(void* const* d_in, const int* in_sizes, int n_in,
                              void* d_out, int out_size, void* d_ws, size_t ws_size,
                              hipStream_t stream) {
    const float* x = (const float*)d_in[0];
    const int* idx = (const int*)d_in[1];
    const float* W = (const float*)d_in[2];
    const float* b = (const float*)d_in[3];
    float* out = (float*)d_out;

    const int N = in_sizes[0] / 128;    // 50000
    const int E = in_sizes[1] / 2;      // 800000
    const int nbins = (N + 255) / 256;  // 196 (<= 256 required)
    const int nrows = nbins * 256;      // 50176 (covers pad row N)
    const int ncast = nbins * 4;        // 784 blocks x 4096 dwords = nrows*64

    char* p = (char*)d_ws;
    auto alloc = [&](size_t bytes) {
        char* r = p;
        p += (bytes + 63) & ~(size_t)63;
        return r;
    };
    int* gbin = (int*)alloc((size_t)nbins * NSHARD * 4);  // 12.5 KB
    unsigned int* pairs =
        (unsigned int*)alloc((size_t)nbins * NSHARD * SUBCAP * 4);  // 4.8 MB
    float* dis = (float*)alloc((size_t)nrows * 4);                  // 200 KB
    unsigned int* xs = (unsigned int*)alloc((size_t)nrows * 128 * 2);  // 12.85 MB
    ushort4* wb = (ushort4*)alloc(128 * 128 * 2);                      // 32 KB

    hipMemsetAsync(gbin, 0, (size_t)nbins * NSHARD * sizeof(int), stream);

    // 16 W-cast + 784 xs-cast + 391 binning blocks, all concurrent
    const int bblocks = 16 + ncast + (E + 2047) / 2048;
    k_bin<<<bblocks, 256, 0, stream>>>(idx, gbin, pairs, (const float4*)W, wb,
                                       (const float2*)x, xs, E, ncast, N, nbins);
    k_deg<<<nbins, 1024, 0, stream>>>(pairs, gbin, dis, N);
    k_fused<<<nbins * 4, 512, 0, stream>>>(pairs, gbin, dis, xs, (const v8s*)wb,
                                           b, out, N);
}